// Round 6
// baseline (86.981 us; speedup 1.0000x reference)
//
#include <hip/hip_runtime.h>
#include <stdint.h>

// Segmented kNN graph: M=65536 pts, D=16, 64 segments x 1024 pts, K=16.
// Output: int32 src[M*16] then int32 dst[M*16].
//
// v15 = v14's candidate-split retried with a VGPR diet so 2 blocks/CU can
// actually be resident. Launch-bounds decode from v10/v11 datapoints is
// CUDA-style min-BLOCKS: (1024,4)->cap32 (measured), (1024,1)->cap128
// (natural 64, measured v13). So (1024,2) caps at exactly 64 = v13's
// natural usage, and v14's exchange chain (+~6 live regs) either spilled
// or blocked 2-blocks/CU residency -> occupancy never doubled, leaving
// only doubled staging + exchange overhead (78->86us). v15 cuts the h=0
// hot-path registers and work:
//  - asymmetric exchange: only h=1 extracts/writes its top-16 quad list
//    (15 cndmask + 16 conflict-free lane writes); h=0 only reads.
//  - h=1 waves RETURN after the exchange barrier (skip keep16, repair,
//    sort16(R), mergeg(R), epilogue) -> 8 h=0 waves/block get double
//    issue bandwidth for the serial tail.
//  - R and partner-read scoped inside h==0; sxc = 512B.
// Target: 2 blocks/CU = 32 waves/CU (v13 showed 55% all-pipe-idle at 16).
//
// Carried: quad-id keys (f32 quad-min via min3+min, 8-bit global qid);
// repair via 4 MFMA tiles over all 64 winner-members (wave-uniform row
// select, contiguous ssq b128 C-operand); top-16 of R alone is exact;
// norms via 4-lane shfl reduce; query f16 from -2c tile by exact *(-0.5).
// Keys: quad = f32bits&~0xFF | qid(8b); member = f32bits&~0x3FF | idx(10b).
// MFMA 16x16x16f16, C operand carries |c|^2+128.

#define L_SEG 1024
#define M_PTS 65536

typedef __fp16 fp16x2 __attribute__((ext_vector_type(2)));
typedef __fp16 fp16x4 __attribute__((ext_vector_type(4)));
typedef float  f32x4  __attribute__((ext_vector_type(4)));

__device__ __forceinline__ uint32_t umn(uint32_t a, uint32_t b) { return a < b ? a : b; }
__device__ __forceinline__ uint32_t umx(uint32_t a, uint32_t b) { return a > b ? a : b; }

#define CE(arr, i, p) { uint32_t lo = umn(arr[i], arr[p]); uint32_t hi = umx(arr[i], arr[p]); arr[i] = lo; arr[p] = hi; }

// bitonic clean of 16 (input bitonic, output sorted ascending): 32 CEs
__device__ __forceinline__ void clean16(uint32_t* A) {
    #pragma unroll
    for (int j = 8; j > 0; j >>= 1) {
        #pragma unroll
        for (int i = 0; i < 16; ++i) {
            int p = i ^ j;
            if (p > i) CE(A, i, p);
        }
    }
}

// Batcher odd-even mergesort-16, ascending (63 CEs)
__device__ __forceinline__ void sort16(uint32_t* B) {
    #pragma unroll
    for (int p = 1; p < 16; p <<= 1) {
        #pragma unroll
        for (int k = p; k >= 1; k >>= 1) {
            #pragma unroll
            for (int j = (k & (p - 1)); j + k < 16; j += 2 * k) {
                #pragma unroll
                for (int i = 0; i <= ((k - 1 < 15 - j - k) ? k - 1 : 15 - j - k); ++i) {
                    if ((i + j) / (2 * p) == (i + j + k) / (2 * p)) CE(B, i + j, i + j + k);
                }
            }
        }
    }
}

// merge sorted S (descending-taken) into sorted A, keep lowest 16
__device__ __forceinline__ void keep16(uint32_t* A, const uint32_t* S) {
    #pragma unroll
    for (int i = 0; i < 16; ++i) A[i] = umn(A[i], S[15 - i]);
    clean16(A);
}

// cross-lane merges over g (xor 16 then 32): disjoint contents per lane
__device__ __forceinline__ void mergeg(uint32_t* A) {
    #pragma unroll
    for (int m = 16; m <= 32; m <<= 1) {
        uint32_t P[16];
        #pragma unroll
        for (int i = 0; i < 16; ++i) P[i] = (uint32_t)__shfl_xor((int)A[15 - i], m, 64);
        #pragma unroll
        for (int i = 0; i < 16; ++i) A[i] = umn(A[i], P[i]);
        clean16(A);
    }
}

__device__ __forceinline__ uint32_t sel4(const uint32_t* A, int g, int v) {
    uint32_t t01 = (g & 1) ? A[4 + v]  : A[v];
    uint32_t t23 = (g & 1) ? A[12 + v] : A[8 + v];
    return (g & 2) ? t23 : t01;
}

__global__ __launch_bounds__(1024, 2) void knn_v15_kernel(const float* __restrict__ x,
                                                          int* __restrict__ out) {
    __shared__ __attribute__((aligned(16))) __fp16 sc[L_SEG * 16];   // -2*c, [cand][dim], 32KB
    __shared__ __attribute__((aligned(16))) float  ssq[L_SEG];       // |c|^2 + 128 (f32), 4KB
    __shared__ __attribute__((aligned(16))) uint32_t sxc[8][16];     // h=1 -> h=0 exchange, 512B

    const int tid  = threadIdx.x;
    const int b    = blockIdx.x;
    const int seg  = b >> 3;          // 8 blocks per segment
    const int qgrp = (b & 7) << 7;    // 128 queries per block
    const float* xseg = x + (size_t)seg * (L_SEG * 16);
    const f32x4* gx4  = (const f32x4*)xseg;

    // ---- stage coords * -2 as f16 [cand][dim]; norms via 4-lane shfl reduce ----
    {
        fp16x4* scv = (fp16x4*)sc;
        #pragma unroll
        for (int i = 0; i < 4; ++i) {
            f32x4 v = gx4[tid + 1024 * i];            // coalesced: 16B/lane contiguous
            union { fp16x2 h2[2]; fp16x4 h4; } u;
            u.h2[0] = __builtin_amdgcn_cvt_pkrtz(-2.0f * v[0], -2.0f * v[1]);
            u.h2[1] = __builtin_amdgcn_cvt_pkrtz(-2.0f * v[2], -2.0f * v[3]);
            scv[tid + 1024 * i] = u.h4;
            // lanes t, t^1, t^2, t^3 hold the 4 dim-quads of cand (t>>2)+256i
            float p = v[0] * v[0];
            p = __builtin_fmaf(v[1], v[1], p);
            p = __builtin_fmaf(v[2], v[2], p);
            p = __builtin_fmaf(v[3], v[3], p);
            p += __shfl_xor(p, 1, 64);
            p += __shfl_xor(p, 2, 64);
            if ((tid & 3) == 0) ssq[(tid >> 2) + 256 * i] = p + 128.0f;
        }
    }
    __syncthreads();

    const int lane = tid & 63;
    const int w    = tid >> 6;        // wave 0..15
    const int qg   = w >> 1;          // query group 0..7 (16 queries each)
    const int h    = w & 1;           // candidate half: cands h*512 .. h*512+511
    const int g    = lane >> 4;       // lane owns quad (tilequad + g)
    const int col  = lane & 15;       // query column
    const int qrow = qgrp + qg * 16 + col;  // query local index in segment

    const fp16x4 mh = {(__fp16)-0.5f, (__fp16)-0.5f, (__fp16)-0.5f, (__fp16)-0.5f};
    // B fragment: rtz(q) recovered exactly from staged rtz(-2q) via *(-0.5)
    fp16x4 bfrag;
    {
        fp16x4 raw = *(const fp16x4*)(sc + (size_t)qrow * 16 + g * 4);
        bfrag = raw * mh;
    }

    const __fp16* ap  = sc + (size_t)col * 16 + g * 4;   // + cand*16 halves
    const float*  sqp = ssq + g * 4;
    const int     hb  = h * 512;      // this wave's candidate-half base

    uint32_t A[16];
    {   // chunk 0: A = sorted(P) directly (keep16 vs +inf is a copy)
        uint32_t P[16];
        #pragma unroll
        for (int t = 0; t < 16; ++t) {
            const int cb = hb + t * 16;
            fp16x4 af = *(const fp16x4*)(ap + (size_t)cb * 16);
            f32x4  sq = *(const f32x4*)(sqp + cb);
            f32x4 acc = __builtin_amdgcn_mfma_f32_16x16x16f16(af, bfrag, sq, 0, 0, 0);
            float m = fminf(fminf(fminf(acc[0], acc[1]), acc[2]), acc[3]);
            P[t] = (__float_as_uint(m) & 0xFFFFFF00u) | (uint32_t)(h * 128 + t * 4) | (uint32_t)g;
        }
        sort16(P);
        #pragma unroll
        for (int i = 0; i < 16; ++i) A[i] = P[i];
    }
    {   // chunk 1
        uint32_t P[16];
        #pragma unroll
        for (int t = 0; t < 16; ++t) {
            const int cb = hb + 256 + t * 16;
            fp16x4 af = *(const fp16x4*)(ap + (size_t)cb * 16);
            f32x4  sq = *(const f32x4*)(sqp + cb);
            f32x4 acc = __builtin_amdgcn_mfma_f32_16x16x16f16(af, bfrag, sq, 0, 0, 0);
            float m = fminf(fminf(fminf(acc[0], acc[1]), acc[2]), acc[3]);
            P[t] = (__float_as_uint(m) & 0xFFFFFF00u) | (uint32_t)(h * 128 + 64 + t * 4) | (uint32_t)g;
        }
        sort16(P);
        keep16(A, P);
    }

    mergeg(A);  // all lanes of this wave: identical sorted top-16 quads of its half

    // ---- asymmetric exchange: h=1 publishes its list, h=0 consumes ----
    if (h) {
        // element index e = 4*col + g (col<4 writers). value = A[4*col+g]:
        // select by g within each quad (12 cndmask), then by col (3).
        const uint32_t t0 = (g & 2) ? ((g & 1) ? A[3]  : A[2])  : ((g & 1) ? A[1]  : A[0]);
        const uint32_t t1 = (g & 2) ? ((g & 1) ? A[7]  : A[6])  : ((g & 1) ? A[5]  : A[4]);
        const uint32_t t2 = (g & 2) ? ((g & 1) ? A[11] : A[10]) : ((g & 1) ? A[9]  : A[8]);
        const uint32_t t3 = (g & 2) ? ((g & 1) ? A[15] : A[14]) : ((g & 1) ? A[13] : A[12]);
        const uint32_t u01 = (col & 1) ? t1 : t0;
        const uint32_t u23 = (col & 1) ? t3 : t2;
        const uint32_t e   = (col & 2) ? u23 : u01;
        if (col < 4) sxc[qg][(col << 2) | g] = e;   // 16 lanes, 16 distinct banks
    }
    __syncthreads();
    if (h) return;    // h=1 waves done; h=0 waves inherit their issue slots

    {   // merge partner's sorted top-16 quad list (broadcast b128 reads)
        uint32_t S[16];
        const uint4* pp = (const uint4*)&sxc[qg][0];
        #pragma unroll
        for (int j = 0; j < 4; ++j) {
            uint4 t4 = pp[j];
            S[4*j+0] = t4.x; S[4*j+1] = t4.y; S[4*j+2] = t4.z; S[4*j+3] = t4.w;
        }
        keep16(A, S);                  // global top-16 quads
    }

    // ---- repair via MFMA: distances of all 64 winner-members x 16 queries ----
    uint32_t R[16];
    {
        const uint32_t c2a = (uint32_t)(col & 4);   // (col>>2)&1
        const uint32_t c2b = (uint32_t)(col & 8);   // (col>>2)&2
        const uint32_t v0  = (uint32_t)(col & 3);
        #pragma unroll
        for (int j = 0; j < 4; ++j) {
            // A-operand: row = col -> member index from A[4j + (col>>2)]
            const uint32_t t01 = c2a ? A[4*j + 1] : A[4*j + 0];
            const uint32_t t23 = c2a ? A[4*j + 3] : A[4*j + 2];
            const uint32_t awc = c2b ? t23 : t01;
            const uint32_t mrow = ((awc & 255u) << 2) | v0;
            fp16x4 af = *(const fp16x4*)(sc + (size_t)mrow * 16 + g * 4);
            // C-operand + key base: rows 4g..4g+3 -> quad A[4j + g]
            const uint32_t u01 = (g & 1) ? A[4*j + 1] : A[4*j + 0];
            const uint32_t u23 = (g & 1) ? A[4*j + 3] : A[4*j + 2];
            const uint32_t awg = (g & 2) ? u23 : u01;
            const uint32_t ib  = (awg & 255u) << 2;          // first member cand
            f32x4 sq = *(const f32x4*)(ssq + (size_t)ib);    // contiguous b128
            f32x4 acc = __builtin_amdgcn_mfma_f32_16x16x16f16(af, bfrag, sq, 0, 0, 0);
            R[j*4 + 0] = (__float_as_uint(acc[0]) & 0xFFFFFC00u) | ib;
            R[j*4 + 1] = (__float_as_uint(acc[1]) & 0xFFFFFC00u) | (ib + 1u);
            R[j*4 + 2] = (__float_as_uint(acc[2]) & 0xFFFFFC00u) | (ib + 2u);
            R[j*4 + 3] = (__float_as_uint(acc[3]) & 0xFFFFFC00u) | (ib + 3u);
        }
    }
    sort16(R);
    mergeg(R);  // 64 member-distances across g-lanes -> exact final top-16

    // ---- epilogue: lane (g,col) writes int4 #g of src and dst for its query ----
    const int base = seg * L_SEG;
    const int q    = base + qrow;
    int4 sv;
    sv.x = base + (int)(sel4(R, g, 0) & 1023u);
    sv.y = base + (int)(sel4(R, g, 1) & 1023u);
    sv.z = base + (int)(sel4(R, g, 2) & 1023u);
    sv.w = base + (int)(sel4(R, g, 3) & 1023u);
    ((int4*)out)[(size_t)q * 4 + g] = sv;
    ((int4*)out)[(size_t)M_PTS * 4 + (size_t)q * 4 + g] = make_int4(q, q, q, q);
}

extern "C" void kernel_launch(void* const* d_in, const int* in_sizes, int n_in,
                              void* d_out, int out_size, void* d_ws, size_t ws_size,
                              hipStream_t stream) {
    const float* x = (const float*)d_in[0];
    // d_in[1] = segs (int64, all 1024) — static per problem setup, unused.
    int* out = (int*)d_out;
    (void)d_ws; (void)ws_size;
    knn_v15_kernel<<<dim3(512), dim3(1024), 0, stream>>>(x, out);
}

// Round 7
// 76.360 us; speedup vs baseline: 1.1391x; 1.1391x over previous
//
#include <hip/hip_runtime.h>
#include <stdint.h>

// Segmented kNN graph: M=65536 pts, D=16, 64 segments x 1024 pts, K=16.
// Output: int32 src[M*16] then int32 dst[M*16].
//
// v16 = v12 + XOR-swizzled sc layout to kill the main-loop LDS bank
// conflicts. Occupancy pivots (v14/v15, 2 blocks/CU) both regressed ->
// bottleneck is a per-CU shared pipe, not wave count. v13 measured
// SQ_LDS_BANK_CONFLICT = 3.35M cyc/rep = ~13k cyc/CU. Audit: the af
// ds_read_b64 at byte (cb+col)*32 + g*8 has quarter-wave bank index
// 8*(col&3)+2g -- col>>2 never enters -> lanes col={0,4,8,12} same bank,
// 4 distinct addrs = 4-way conflict on EVERY main-loop read (64 tiles x
// ~12 extra cyc x 16 waves ~= 12k cyc/CU: matches). Fix: store cand's
// dim-quad d at slot d ^ ((cand>>2)&3). Bank becomes 8*(col&3)+2*(g^
// (col>>2)) -> 16 distinct banks, conflict-free. Swizzle term is
// loop-invariant per lane -> folds into the ap/bfrag base pointers,
// zero hot-loop VALU; staging write folds into one precomputed index;
// repair pays 2 ops/tile x 4 tiles.
//
// Carried from v12: quad-id keys (f32 quad-min via min3+min, 8-bit qid);
// repair via 4 MFMA tiles over all 64 winner-members (wave-uniform row
// select, contiguous ssq b128 C-operand); top-16 of R alone is exact;
// iter-0 A=sorted(P); 1024-thr blocks, 256 q/block, grid 256,
// __launch_bounds__(1024,1); norms via 4-lane shfl reduce; query f16
// recovered from -2c tile by exact *(-0.5).
// Keys: quad = f32bits&~0xFF | qid(8b); member = f32bits&~0x3FF | idx(10b).
// MFMA 16x16x16f16, C operand carries |c|^2+128.

#define L_SEG 1024
#define M_PTS 65536

typedef __fp16 fp16x2 __attribute__((ext_vector_type(2)));
typedef __fp16 fp16x4 __attribute__((ext_vector_type(4)));
typedef float  f32x4  __attribute__((ext_vector_type(4)));

__device__ __forceinline__ uint32_t umn(uint32_t a, uint32_t b) { return a < b ? a : b; }
__device__ __forceinline__ uint32_t umx(uint32_t a, uint32_t b) { return a > b ? a : b; }

#define CE(arr, i, p) { uint32_t lo = umn(arr[i], arr[p]); uint32_t hi = umx(arr[i], arr[p]); arr[i] = lo; arr[p] = hi; }

// bitonic clean of 16 (input bitonic, output sorted ascending): 32 CEs
__device__ __forceinline__ void clean16(uint32_t* A) {
    #pragma unroll
    for (int j = 8; j > 0; j >>= 1) {
        #pragma unroll
        for (int i = 0; i < 16; ++i) {
            int p = i ^ j;
            if (p > i) CE(A, i, p);
        }
    }
}

// Batcher odd-even mergesort-16, ascending (63 CEs)
__device__ __forceinline__ void sort16(uint32_t* B) {
    #pragma unroll
    for (int p = 1; p < 16; p <<= 1) {
        #pragma unroll
        for (int k = p; k >= 1; k >>= 1) {
            #pragma unroll
            for (int j = (k & (p - 1)); j + k < 16; j += 2 * k) {
                #pragma unroll
                for (int i = 0; i <= ((k - 1 < 15 - j - k) ? k - 1 : 15 - j - k); ++i) {
                    if ((i + j) / (2 * p) == (i + j + k) / (2 * p)) CE(B, i + j, i + j + k);
                }
            }
        }
    }
}

// merge sorted S (descending-taken) into sorted A, keep lowest 16
__device__ __forceinline__ void keep16(uint32_t* A, const uint32_t* S) {
    #pragma unroll
    for (int i = 0; i < 16; ++i) A[i] = umn(A[i], S[15 - i]);
    clean16(A);
}

// cross-lane merges over g (xor 16 then 32): disjoint contents per lane
__device__ __forceinline__ void mergeg(uint32_t* A) {
    #pragma unroll
    for (int m = 16; m <= 32; m <<= 1) {
        uint32_t P[16];
        #pragma unroll
        for (int i = 0; i < 16; ++i) P[i] = (uint32_t)__shfl_xor((int)A[15 - i], m, 64);
        #pragma unroll
        for (int i = 0; i < 16; ++i) A[i] = umn(A[i], P[i]);
        clean16(A);
    }
}

__device__ __forceinline__ uint32_t sel4(const uint32_t* A, int g, int v) {
    uint32_t t01 = (g & 1) ? A[4 + v]  : A[v];
    uint32_t t23 = (g & 1) ? A[12 + v] : A[8 + v];
    return (g & 2) ? t23 : t01;
}

__global__ __launch_bounds__(1024, 1) void knn_v16_kernel(const float* __restrict__ x,
                                                          int* __restrict__ out) {
    // sc layout: cand's dim-quad d stored at fp16x4 slot cand*4 + (d ^ ((cand>>2)&3))
    __shared__ __attribute__((aligned(16))) __fp16 sc[L_SEG * 16];  // -2*c, swizzled, 32KB
    __shared__ __attribute__((aligned(16))) float  ssq[L_SEG];      // |c|^2 + 128 (f32), 4KB

    const int tid  = threadIdx.x;
    const int b    = blockIdx.x;
    const int seg  = b >> 2;          // 4 blocks per segment
    const int qgrp = (b & 3) << 8;    // 256 queries per block
    const float* xseg = x + (size_t)seg * (L_SEG * 16);
    const f32x4* gx4  = (const f32x4*)xseg;

    // ---- stage coords * -2 as f16 (swizzled slot); norms via 4-lane shfl reduce ----
    {
        fp16x4* scv = (fp16x4*)sc;
        // thread tid handles dim-quad (tid&3) of cand (tid>>2)+256i;
        // (cand>>2)&3 = (tid>>4)&3 (i-invariant since 64i = 0 mod 4)
        const int widx = (tid & ~3) + ((tid & 3) ^ ((tid >> 4) & 3));
        #pragma unroll
        for (int i = 0; i < 4; ++i) {
            f32x4 v = gx4[tid + 1024 * i];            // coalesced: 16B/lane contiguous
            union { fp16x2 h2[2]; fp16x4 h4; } u;
            u.h2[0] = __builtin_amdgcn_cvt_pkrtz(-2.0f * v[0], -2.0f * v[1]);
            u.h2[1] = __builtin_amdgcn_cvt_pkrtz(-2.0f * v[2], -2.0f * v[3]);
            scv[widx + 1024 * i] = u.h4;
            // lanes t, t^1, t^2, t^3 hold the 4 dim-quads of cand (t>>2)+256i
            float p = v[0] * v[0];
            p = __builtin_fmaf(v[1], v[1], p);
            p = __builtin_fmaf(v[2], v[2], p);
            p = __builtin_fmaf(v[3], v[3], p);
            p += __shfl_xor(p, 1, 64);
            p += __shfl_xor(p, 2, 64);
            if ((tid & 3) == 0) ssq[(tid >> 2) + 256 * i] = p + 128.0f;
        }
    }
    __syncthreads();

    const int lane = tid & 63;
    const int w    = tid >> 6;        // wave 0..15
    const int g    = lane >> 4;       // lane owns quad (tilequad + g)
    const int col  = lane & 15;       // query column
    const int qrow = qgrp + w * 16 + col;   // query local index in segment
    const int gsw  = g ^ ((col >> 2) & 3);  // swizzled slot for this lane's k-quad

    const fp16x4 mh = {(__fp16)-0.5f, (__fp16)-0.5f, (__fp16)-0.5f, (__fp16)-0.5f};
    // B fragment: rtz(q) recovered exactly from staged rtz(-2q) via *(-0.5).
    // qrow's swizzle = g ^ ((qrow>>2)&3) = gsw (qgrp,w*16 are 0 mod 4 after >>2).
    fp16x4 bfrag;
    {
        fp16x4 raw = *(const fp16x4*)(sc + (size_t)qrow * 16 + gsw * 4);
        bfrag = raw * mh;
    }

    // af base: cand cb+col, k-quad g -> slot g ^ (((cb+col)>>2)&3) = gsw
    // (cb is a multiple of 16). Loop-invariant -> fold into ap.
    const __fp16* ap  = sc + (size_t)col * 16 + gsw * 4;   // + cand*16 halves
    const float*  sqp = ssq + g * 4;

    uint32_t A[16];
    {   // iter 0: A = sorted(P) directly (keep16 vs +inf is a copy)
        uint32_t P[16];
        #pragma unroll
        for (int t = 0; t < 16; ++t) {
            const int cb = t * 16;
            fp16x4 af = *(const fp16x4*)(ap + (size_t)cb * 16);
            f32x4  sq = *(const f32x4*)(sqp + cb);
            f32x4 acc = __builtin_amdgcn_mfma_f32_16x16x16f16(af, bfrag, sq, 0, 0, 0);
            float m = fminf(fminf(fminf(acc[0], acc[1]), acc[2]), acc[3]);
            P[t] = (__float_as_uint(m) & 0xFFFFFF00u) | (uint32_t)(t * 4) | (uint32_t)g;
        }
        sort16(P);
        #pragma unroll
        for (int i = 0; i < 16; ++i) A[i] = P[i];
    }
    #pragma unroll
    for (int it = 1; it < 4; ++it) {
        uint32_t P[16];
        #pragma unroll
        for (int t = 0; t < 16; ++t) {
            const int cb = it * 256 + t * 16;
            fp16x4 af = *(const fp16x4*)(ap + (size_t)cb * 16);
            f32x4  sq = *(const f32x4*)(sqp + cb);
            f32x4 acc = __builtin_amdgcn_mfma_f32_16x16x16f16(af, bfrag, sq, 0, 0, 0);
            float m = fminf(fminf(fminf(acc[0], acc[1]), acc[2]), acc[3]);
            P[t] = (__float_as_uint(m) & 0xFFFFFF00u) | (uint32_t)(it * 64 + t * 4) | (uint32_t)g;
        }
        sort16(P);
        keep16(A, P);
    }

    mergeg(A);  // all lanes now hold the IDENTICAL sorted top-16 quad keys

    // ---- repair via MFMA: distances of all 64 winner-members x 16 queries ----
    uint32_t R[16];
    {
        const uint32_t c2a = (uint32_t)(col & 4);   // (col>>2)&1
        const uint32_t c2b = (uint32_t)(col & 8);   // (col>>2)&2
        const uint32_t v0  = (uint32_t)(col & 3);
        #pragma unroll
        for (int j = 0; j < 4; ++j) {
            // A-operand: row = col -> member index from A[4j + (col>>2)]
            const uint32_t t01 = c2a ? A[4*j + 1] : A[4*j + 0];
            const uint32_t t23 = c2a ? A[4*j + 3] : A[4*j + 2];
            const uint32_t awc = c2b ? t23 : t01;
            const uint32_t qid = awc & 255u;
            const uint32_t mrow = (qid << 2) | v0;
            // swizzled slot for k-quad g of cand mrow: g ^ ((mrow>>2)&3) = g ^ (qid&3)
            const uint32_t msw = ((uint32_t)g ^ (qid & 3u)) << 2;
            fp16x4 af = *(const fp16x4*)(sc + (size_t)mrow * 16 + msw);
            // C-operand + key base: rows 4g..4g+3 -> quad A[4j + g]
            const uint32_t u01 = (g & 1) ? A[4*j + 1] : A[4*j + 0];
            const uint32_t u23 = (g & 1) ? A[4*j + 3] : A[4*j + 2];
            const uint32_t awg = (g & 2) ? u23 : u01;
            const uint32_t ib  = (awg & 255u) << 2;          // first member cand
            f32x4 sq = *(const f32x4*)(ssq + (size_t)ib);    // contiguous b128
            f32x4 acc = __builtin_amdgcn_mfma_f32_16x16x16f16(af, bfrag, sq, 0, 0, 0);
            R[j*4 + 0] = (__float_as_uint(acc[0]) & 0xFFFFFC00u) | ib;
            R[j*4 + 1] = (__float_as_uint(acc[1]) & 0xFFFFFC00u) | (ib + 1u);
            R[j*4 + 2] = (__float_as_uint(acc[2]) & 0xFFFFFC00u) | (ib + 2u);
            R[j*4 + 3] = (__float_as_uint(acc[3]) & 0xFFFFFC00u) | (ib + 3u);
        }
    }
    sort16(R);
    mergeg(R);  // 64 member-distances across g-lanes -> exact final top-16

    // ---- epilogue: lane (g,col) writes int4 #g of src and dst for its query ----
    const int base = seg * L_SEG;
    const int q    = base + qrow;
    int4 sv;
    sv.x = base + (int)(sel4(R, g, 0) & 1023u);
    sv.y = base + (int)(sel4(R, g, 1) & 1023u);
    sv.z = base + (int)(sel4(R, g, 2) & 1023u);
    sv.w = base + (int)(sel4(R, g, 3) & 1023u);
    ((int4*)out)[(size_t)q * 4 + g] = sv;
    ((int4*)out)[(size_t)M_PTS * 4 + (size_t)q * 4 + g] = make_int4(q, q, q, q);
}

extern "C" void kernel_launch(void* const* d_in, const int* in_sizes, int n_in,
                              void* d_out, int out_size, void* d_ws, size_t ws_size,
                              hipStream_t stream) {
    const float* x = (const float*)d_in[0];
    // d_in[1] = segs (int64, all 1024) — static per problem setup, unused.
    int* out = (int*)d_out;
    (void)d_ws; (void)ws_size;
    knn_v16_kernel<<<dim3(256), dim3(1024), 0, stream>>>(x, out);
}

// Round 8
// 74.892 us; speedup vs baseline: 1.1614x; 1.0196x over previous
//
#include <hip/hip_runtime.h>
#include <stdint.h>

// Segmented kNN graph: M=65536 pts, D=16, 64 segments x 1024 pts, K=16.
// Output: int32 src[M*16] then int32 dst[M*16].
//
// v17 = v16 with the main-loop selection DEPENDENCY TREE FLATTENED.
// v16 analysis: dur = fill(~44) + kernel(~22) + overhead(~10). Kernel VALU
// issue ~6k cyc/wave (VALUBusy 45%), ideal-overlap floor ~13-15us -> ~7us
// of dependency stalls. The serial chain is the accumulator structure:
// sort16 -> keep16(A,.) -> sort16 -> keep16(A,.) -> ... (7 dependent
// selection stages). Occupancy is GRID-PINNED at 16 waves/CU (grid=256 =
// 1 block/CU; grid-512 variants v14/v15 both regressed), so VGPRs up to
// the 128 cap are free -> spend them on ILP: compute 4 INDEPENDENT key
// batches P0..P3 (64 MFMA tiles), 4 independent sort16s, then a balanced
// merge tree keep16(P0,P1); keep16(P2,P3); keep16(P0,P2). Same VALU count
// (744), same key set -> bit-identical result; critical path 7 -> 3
// stages, and the scheduler can interleave 4 sort networks with MFMA/DS
// latency. Live set ~100 VGPR, harmless (occupancy unchanged).
//
// Carried from v16: XOR-swizzled sc layout (cand's dim-quad d at slot
// d ^ ((cand>>2)&3)) -> conflict-free main-loop/staging LDS, swizzle term
// folds into base pointers; quad-id keys (f32 quad-min via min3+min,
// 8-bit qid); repair via 4 MFMA tiles over all 64 winner-members
// (wave-uniform row select, contiguous ssq b128 C-operand); top-16 of R
// alone is exact; 1024-thr blocks, 256 q/block, grid 256,
// __launch_bounds__(1024,1); norms via 4-lane shfl reduce; query f16
// recovered from -2c tile by exact *(-0.5).
// Keys: quad = f32bits&~0xFF | qid(8b); member = f32bits&~0x3FF | idx(10b).
// MFMA 16x16x16f16, C operand carries |c|^2+128.

#define L_SEG 1024
#define M_PTS 65536

typedef __fp16 fp16x2 __attribute__((ext_vector_type(2)));
typedef __fp16 fp16x4 __attribute__((ext_vector_type(4)));
typedef float  f32x4  __attribute__((ext_vector_type(4)));

__device__ __forceinline__ uint32_t umn(uint32_t a, uint32_t b) { return a < b ? a : b; }
__device__ __forceinline__ uint32_t umx(uint32_t a, uint32_t b) { return a > b ? a : b; }

#define CE(arr, i, p) { uint32_t lo = umn(arr[i], arr[p]); uint32_t hi = umx(arr[i], arr[p]); arr[i] = lo; arr[p] = hi; }

// bitonic clean of 16 (input bitonic, output sorted ascending): 32 CEs
__device__ __forceinline__ void clean16(uint32_t* A) {
    #pragma unroll
    for (int j = 8; j > 0; j >>= 1) {
        #pragma unroll
        for (int i = 0; i < 16; ++i) {
            int p = i ^ j;
            if (p > i) CE(A, i, p);
        }
    }
}

// Batcher odd-even mergesort-16, ascending (63 CEs)
__device__ __forceinline__ void sort16(uint32_t* B) {
    #pragma unroll
    for (int p = 1; p < 16; p <<= 1) {
        #pragma unroll
        for (int k = p; k >= 1; k >>= 1) {
            #pragma unroll
            for (int j = (k & (p - 1)); j + k < 16; j += 2 * k) {
                #pragma unroll
                for (int i = 0; i <= ((k - 1 < 15 - j - k) ? k - 1 : 15 - j - k); ++i) {
                    if ((i + j) / (2 * p) == (i + j + k) / (2 * p)) CE(B, i + j, i + j + k);
                }
            }
        }
    }
}

// merge sorted S (descending-taken) into sorted A, keep lowest 16
__device__ __forceinline__ void keep16(uint32_t* A, const uint32_t* S) {
    #pragma unroll
    for (int i = 0; i < 16; ++i) A[i] = umn(A[i], S[15 - i]);
    clean16(A);
}

// cross-lane merges over g (xor 16 then 32): disjoint contents per lane
__device__ __forceinline__ void mergeg(uint32_t* A) {
    #pragma unroll
    for (int m = 16; m <= 32; m <<= 1) {
        uint32_t P[16];
        #pragma unroll
        for (int i = 0; i < 16; ++i) P[i] = (uint32_t)__shfl_xor((int)A[15 - i], m, 64);
        #pragma unroll
        for (int i = 0; i < 16; ++i) A[i] = umn(A[i], P[i]);
        clean16(A);
    }
}

__device__ __forceinline__ uint32_t sel4(const uint32_t* A, int g, int v) {
    uint32_t t01 = (g & 1) ? A[4 + v]  : A[v];
    uint32_t t23 = (g & 1) ? A[12 + v] : A[8 + v];
    return (g & 2) ? t23 : t01;
}

// one 256-cand batch: 16 MFMA tiles -> 16 packed quad-min keys (unsorted)
__device__ __forceinline__ void batch16(const __fp16* ap, const float* sqp,
                                        fp16x4 bfrag, int it, int g, uint32_t* P) {
    #pragma unroll
    for (int t = 0; t < 16; ++t) {
        const int cb = it * 256 + t * 16;
        fp16x4 af = *(const fp16x4*)(ap + (size_t)cb * 16);
        f32x4  sq = *(const f32x4*)(sqp + cb);
        f32x4 acc = __builtin_amdgcn_mfma_f32_16x16x16f16(af, bfrag, sq, 0, 0, 0);
        float m = fminf(fminf(fminf(acc[0], acc[1]), acc[2]), acc[3]);
        P[t] = (__float_as_uint(m) & 0xFFFFFF00u) | (uint32_t)(it * 64 + t * 4) | (uint32_t)g;
    }
}

__global__ __launch_bounds__(1024, 1) void knn_v17_kernel(const float* __restrict__ x,
                                                          int* __restrict__ out) {
    // sc layout: cand's dim-quad d stored at fp16x4 slot cand*4 + (d ^ ((cand>>2)&3))
    __shared__ __attribute__((aligned(16))) __fp16 sc[L_SEG * 16];  // -2*c, swizzled, 32KB
    __shared__ __attribute__((aligned(16))) float  ssq[L_SEG];      // |c|^2 + 128 (f32), 4KB

    const int tid  = threadIdx.x;
    const int b    = blockIdx.x;
    const int seg  = b >> 2;          // 4 blocks per segment
    const int qgrp = (b & 3) << 8;    // 256 queries per block
    const float* xseg = x + (size_t)seg * (L_SEG * 16);
    const f32x4* gx4  = (const f32x4*)xseg;

    // ---- stage coords * -2 as f16 (swizzled slot); norms via 4-lane shfl reduce ----
    {
        fp16x4* scv = (fp16x4*)sc;
        // thread tid handles dim-quad (tid&3) of cand (tid>>2)+256i;
        // (cand>>2)&3 = (tid>>4)&3 (i-invariant since 64i = 0 mod 4)
        const int widx = (tid & ~3) + ((tid & 3) ^ ((tid >> 4) & 3));
        #pragma unroll
        for (int i = 0; i < 4; ++i) {
            f32x4 v = gx4[tid + 1024 * i];            // coalesced: 16B/lane contiguous
            union { fp16x2 h2[2]; fp16x4 h4; } u;
            u.h2[0] = __builtin_amdgcn_cvt_pkrtz(-2.0f * v[0], -2.0f * v[1]);
            u.h2[1] = __builtin_amdgcn_cvt_pkrtz(-2.0f * v[2], -2.0f * v[3]);
            scv[widx + 1024 * i] = u.h4;
            // lanes t, t^1, t^2, t^3 hold the 4 dim-quads of cand (t>>2)+256i
            float p = v[0] * v[0];
            p = __builtin_fmaf(v[1], v[1], p);
            p = __builtin_fmaf(v[2], v[2], p);
            p = __builtin_fmaf(v[3], v[3], p);
            p += __shfl_xor(p, 1, 64);
            p += __shfl_xor(p, 2, 64);
            if ((tid & 3) == 0) ssq[(tid >> 2) + 256 * i] = p + 128.0f;
        }
    }
    __syncthreads();

    const int lane = tid & 63;
    const int w    = tid >> 6;        // wave 0..15
    const int g    = lane >> 4;       // lane owns quad (tilequad + g)
    const int col  = lane & 15;       // query column
    const int qrow = qgrp + w * 16 + col;   // query local index in segment
    const int gsw  = g ^ ((col >> 2) & 3);  // swizzled slot for this lane's k-quad

    const fp16x4 mh = {(__fp16)-0.5f, (__fp16)-0.5f, (__fp16)-0.5f, (__fp16)-0.5f};
    // B fragment: rtz(q) recovered exactly from staged rtz(-2q) via *(-0.5).
    // qrow's swizzle = g ^ ((qrow>>2)&3) = gsw (qgrp,w*16 are 0 mod 4 after >>2).
    fp16x4 bfrag;
    {
        fp16x4 raw = *(const fp16x4*)(sc + (size_t)qrow * 16 + gsw * 4);
        bfrag = raw * mh;
    }

    // af base: cand cb+col, k-quad g -> slot g ^ (((cb+col)>>2)&3) = gsw
    // (cb is a multiple of 16). Loop-invariant -> fold into ap.
    const __fp16* ap  = sc + (size_t)col * 16 + gsw * 4;   // + cand*16 halves
    const float*  sqp = ssq + g * 4;

    // ---- 4 independent batches -> 4 independent sorts -> balanced merge tree ----
    uint32_t P0[16], P1[16], P2[16], P3[16];
    batch16(ap, sqp, bfrag, 0, g, P0);
    batch16(ap, sqp, bfrag, 1, g, P1);
    batch16(ap, sqp, bfrag, 2, g, P2);
    batch16(ap, sqp, bfrag, 3, g, P3);
    sort16(P0);
    sort16(P1);
    sort16(P2);
    sort16(P3);
    keep16(P0, P1);   // top-16 of batches 0,1
    keep16(P2, P3);   // top-16 of batches 2,3
    keep16(P0, P2);   // per-lane top-16 of all 64 quad keys
    uint32_t* A = P0;

    mergeg(A);  // all lanes now hold the IDENTICAL sorted top-16 quad keys

    // ---- repair via MFMA: distances of all 64 winner-members x 16 queries ----
    uint32_t R[16];
    {
        const uint32_t c2a = (uint32_t)(col & 4);   // (col>>2)&1
        const uint32_t c2b = (uint32_t)(col & 8);   // (col>>2)&2
        const uint32_t v0  = (uint32_t)(col & 3);
        #pragma unroll
        for (int j = 0; j < 4; ++j) {
            // A-operand: row = col -> member index from A[4j + (col>>2)]
            const uint32_t t01 = c2a ? A[4*j + 1] : A[4*j + 0];
            const uint32_t t23 = c2a ? A[4*j + 3] : A[4*j + 2];
            const uint32_t awc = c2b ? t23 : t01;
            const uint32_t qid = awc & 255u;
            const uint32_t mrow = (qid << 2) | v0;
            // swizzled slot for k-quad g of cand mrow: g ^ ((mrow>>2)&3) = g ^ (qid&3)
            const uint32_t msw = ((uint32_t)g ^ (qid & 3u)) << 2;
            fp16x4 af = *(const fp16x4*)(sc + (size_t)mrow * 16 + msw);
            // C-operand + key base: rows 4g..4g+3 -> quad A[4j + g]
            const uint32_t u01 = (g & 1) ? A[4*j + 1] : A[4*j + 0];
            const uint32_t u23 = (g & 1) ? A[4*j + 3] : A[4*j + 2];
            const uint32_t awg = (g & 2) ? u23 : u01;
            const uint32_t ib  = (awg & 255u) << 2;          // first member cand
            f32x4 sq = *(const f32x4*)(ssq + (size_t)ib);    // contiguous b128
            f32x4 acc = __builtin_amdgcn_mfma_f32_16x16x16f16(af, bfrag, sq, 0, 0, 0);
            R[j*4 + 0] = (__float_as_uint(acc[0]) & 0xFFFFFC00u) | ib;
            R[j*4 + 1] = (__float_as_uint(acc[1]) & 0xFFFFFC00u) | (ib + 1u);
            R[j*4 + 2] = (__float_as_uint(acc[2]) & 0xFFFFFC00u) | (ib + 2u);
            R[j*4 + 3] = (__float_as_uint(acc[3]) & 0xFFFFFC00u) | (ib + 3u);
        }
    }
    sort16(R);
    mergeg(R);  // 64 member-distances across g-lanes -> exact final top-16

    // ---- epilogue: lane (g,col) writes int4 #g of src and dst for its query ----
    const int base = seg * L_SEG;
    const int q    = base + qrow;
    int4 sv;
    sv.x = base + (int)(sel4(R, g, 0) & 1023u);
    sv.y = base + (int)(sel4(R, g, 1) & 1023u);
    sv.z = base + (int)(sel4(R, g, 2) & 1023u);
    sv.w = base + (int)(sel4(R, g, 3) & 1023u);
    ((int4*)out)[(size_t)q * 4 + g] = sv;
    ((int4*)out)[(size_t)M_PTS * 4 + (size_t)q * 4 + g] = make_int4(q, q, q, q);
}

extern "C" void kernel_launch(void* const* d_in, const int* in_sizes, int n_in,
                              void* d_out, int out_size, void* d_ws, size_t ws_size,
                              hipStream_t stream) {
    const float* x = (const float*)d_in[0];
    // d_in[1] = segs (int64, all 1024) — static per problem setup, unused.
    int* out = (int*)d_out;
    (void)d_ws; (void)ws_size;
    knn_v17_kernel<<<dim3(256), dim3(1024), 0, stream>>>(x, out);
}